// Round 10
// baseline (162.942 us; speedup 1.0000x reference)
//
#include <hip/hip_runtime.h>
#include <cstdint>
#include <cstddef>

typedef unsigned short u16;
typedef __attribute__((ext_vector_type(8))) __bf16 bf16x8;
typedef __attribute__((ext_vector_type(4))) float f32x4;

__device__ __forceinline__ u16 f2bf(float f) {
  unsigned u = __float_as_uint(f);
  u += 0x7FFFu + ((u >> 16) & 1u);   // round-to-nearest-even
  return (u16)(u >> 16);
}

__device__ __forceinline__ float bf2f(u16 h) {
  return __uint_as_float(((unsigned)h) << 16);
}

__device__ __forceinline__ void async16(u16* lds, const u16* g) {
  __builtin_amdgcn_global_load_lds(
      (const __attribute__((address_space(1))) unsigned int*)g,
      (__attribute__((address_space(3))) unsigned int*)lds, 16, 0, 0);
}

// ---------------- prep: x->bf16 (blocks 0..3071) + TT pre-pass (blocks 3072..4295) ----
__global__ __launch_bounds__(256)
void prep(const float4* __restrict__ x4, ushort4* __restrict__ xb4,
          const float* __restrict__ gA1, const float* __restrict__ gB1,
          const float* __restrict__ gC1, const float* __restrict__ gD1,
          const float* __restrict__ gA2, const float* __restrict__ gB2,
          const float* __restrict__ gC2, const float* __restrict__ gD2,
          float* __restrict__ B12_1, float* __restrict__ B12_2,
          float* __restrict__ C1, float* __restrict__ C2) {
  const int b = blockIdx.x;
  const int tid = threadIdx.x;
  if (b < 3072) {
    int i = b * 256 + tid;
    float4 v = x4[i];
    ushort4 o;
    o.x = f2bf(v.x); o.y = f2bf(v.y); o.z = f2bf(v.z); o.w = f2bf(v.w);
    xb4[i] = o;
    return;
  }
  int idx = (b - 3072) * 256 + tid;
  if (idx < 9216) {
    int e = idx;
    int r2 = e % 24; int t = e / 24;
    int fo12 = t % 24, fi12 = t / 24;
    int i2 = fi12 % 4, i1 = fi12 / 4;
    int o2 = fo12 % 6, o1 = fo12 / 6;
    float s = 0.f;
#pragma unroll
    for (int r1 = 0; r1 < 12; ++r1)
      s += gA1[(i1 * 4 + o1) * 12 + r1] * gB1[((r1 * 4 + i2) * 6 + o2) * 24 + r2];
    B12_1[e] = s;
  } else if (idx < 18432) {
    int e = idx - 9216;
    int r2 = e % 24; int t = e / 24;
    int fo12 = t % 16, fi12 = t / 16;
    int i2 = fi12 % 6, i1 = fi12 / 6;
    int o2 = fo12 % 4, o1 = fo12 / 4;
    float s = 0.f;
#pragma unroll
    for (int r1 = 0; r1 < 12; ++r1)
      s += gA2[(i1 * 4 + o1) * 12 + r1] * gB2[((r1 * 6 + i2) * 4 + o2) * 24 + r2];
    B12_2[e] = s;
  } else if (idx < 165888) {
    int e = idx - 18432;
    int fi34 = e % 48; int t = e / 48;
    int fo34 = t % 128;
    int i3 = fi34 / 8, i4 = fi34 % 8;
    int o3 = fo34 / 16, o4 = fo34 % 16;
    int r2 = t / 128;
    float s = 0.f;
#pragma unroll
    for (int r3 = 0; r3 < 12; ++r3)
      s += gC1[((r2 * 6 + i3) * 8 + o3) * 12 + r3] * gD1[(r3 * 8 + i4) * 16 + o4];
    C1[e] = s;
  } else {
    int e = idx - 165888;
    int fi34 = e % 128; int t = e / 128;
    int fo34 = t % 48;
    int i3 = fi34 / 16, i4 = fi34 % 16;
    int o3 = fo34 / 8, o4 = fo34 % 8;
    int r2 = t / 48;
    float s = 0.f;
#pragma unroll
    for (int r3 = 0; r3 < 12; ++r3)
      s += gC2[((r2 * 8 + i3) * 6 + o3) * 12 + r3] * gD2[(r3 * 16 + i4) * 8 + o4];
    C2[e] = s;
  }
}

// ---------------- TT expand (device body): Wt[out][in] = sum_r2 B12*C34t ----------------
template <int FI12, int I34, int O12, int O34, int OG>
__device__ __forceinline__
void tt_expand_body(const float* __restrict__ B12, const float* __restrict__ C34t,
                    u16* __restrict__ Wt, int bx, int by, int tid, float* sB) {
  constexpr int R2 = 24;
  constexpr int Kin = FI12 * I34;
  constexpr int IC = Kin / 8;
  constexpr int I34C = I34 / 8;
  for (int e = tid; e < FI12 * OG * R2; e += 256) {
    int r2 = e % R2; int t = e / R2;
    int f = t % OG; int fi12 = t / OG;
    sB[(fi12 * OG + f) * 25 + r2] = B12[(fi12 * O12 + by * OG + f) * R2 + r2];
  }
  __syncthreads();
  const int t = bx * 256 + tid;
  const int fo34 = t / IC;
  const int ic = t % IC;
  const int fi12 = ic / I34C;
  const int fi34 = (ic % I34C) * 8;

  float acc[OG][8];
#pragma unroll
  for (int f = 0; f < OG; ++f)
#pragma unroll
    for (int k = 0; k < 8; ++k) acc[f][k] = 0.f;

  for (int r2 = 0; r2 < R2; ++r2) {
    const float4* cp = (const float4*)(C34t + ((size_t)(r2 * O34 + fo34) * I34 + fi34));
    float4 c0 = cp[0], c1 = cp[1];
    float c[8] = {c0.x, c0.y, c0.z, c0.w, c1.x, c1.y, c1.z, c1.w};
#pragma unroll
    for (int f = 0; f < OG; ++f) {
      float bb = sB[(fi12 * OG + f) * 25 + r2];
#pragma unroll
      for (int k = 0; k < 8; ++k) acc[f][k] += bb * c[k];
    }
  }
#pragma unroll
  for (int f = 0; f < OG; ++f) {
    int out = (by * OG + f) * O34 + fo34;
    u16 v[8];
#pragma unroll
    for (int k = 0; k < 8; ++k) v[k] = f2bf(acc[f][k]);
    *(uint4*)(Wt + (size_t)out * Kin + fi12 * I34 + fi34) = *(const uint4*)v;
  }
}

// Merged: blocks 0..287 -> layer1 (48x6); blocks 288..575 -> layer2 (72x4)
__global__ __launch_bounds__(256)
void tt_expand2(const float* __restrict__ B12_1, const float* __restrict__ C1, u16* __restrict__ W1t,
                const float* __restrict__ B12_2, const float* __restrict__ C2, u16* __restrict__ W2t) {
  __shared__ float sB[24 * 4 * 25];
  const int b = blockIdx.x;
  const int tid = threadIdx.x;
  if (b < 288) {
    tt_expand_body<16, 48, 24, 128, 4>(B12_1, C1, W1t, b % 48, b / 48, tid, sB);
  } else {
    int bb = b - 288;
    tt_expand_body<24, 128, 16, 48, 4>(B12_2, C2, W2t, bb % 72, bb / 72, tid, sB);
  }
}

// ---- bf16 MFMA GEMM: R23 = R22 loop (passed, 1 barrier/K-tile) + gemm2-direct ----
// R23: five structurally distinct schedules all land ~36us/gemm (time tracks
// FLOPs, not barriers/conflicts/depth) -> stop schedule surgery; consolidate
// the GEMM2->reduceN8 chain instead. R19 (atomics) failed on cross-XCD atomic
// serialization; R20 (no-split, 256 blocks) failed on TLP (1 blk/CU). This
// variant avoids both: BM=64 x BN=96 tile, grid 64x8 = 512 blocks = 2 blk/CU
// (TLP kept), K=3072 un-split (NT=48, best amortization), each output address
// owned by ONE block -> plain coalesced f32 stores to out, bias folded in.
// Removes Part (25MB bf16 writes) + reduceN8 (25MB rd + 12.6MB wr + launch).
// Ledger generalizes: prologue PA+6 loads -> vmcnt(3) drains A0+B0, B1 in
// flight; per tile stage A(t+1) [PA] + B(t+2) [3]; end-of-tile vmcnt(3)
// drains B(t+1)+A(t+1) exactly (wait-BEFORE-barrier; vmcnt is per-wave).
// MI = BM/32 parameterizes wave rows (BM=128: wm=(wave&1)*64, mi 0..3;
// BM=64: wm=(wave&1)*32, mi 0..1); wm,wn stay multiples of 8 so the 3-bit
// both-sides swizzle (byte ^= (row&7)<<4; source chunk ^= row&7) is unchanged.
template <int EPI, int MAP, int NT, int BM>
__global__ __launch_bounds__(256, 2)
void gemm_bt(const u16* __restrict__ A, const u16* __restrict__ Bt,
             const float* __restrict__ bias, u16* __restrict__ Out,
             float* __restrict__ OutF, int N, int lda, int ldb) {
  constexpr int MI = BM / 32;          // acc rows of 16 per wave half
  constexpr int PA = BM / 32;          // A staging pieces (32 rows each)
  constexpr int ASLOT = BM * 64;       // u16 per A slot
  const int flat = blockIdx.x;
  const int xcd = flat & 7;            // HW round-robins blockIdx over 8 XCDs
  const int local = flat >> 3;
  int bm, bn;
  if (MAP == 1) {                      // GEMM1: 32bm x 32bn; XCD rect 8bm x 16bn
    bm = (xcd >> 1) * 8 + (local & 7);         // local 0..127
    bn = (xcd & 1) * 16 + (local >> 3);
  } else {                             // GEMM2: 64bm x 8bn; XCD rect 8bm x 8bn
    bm = xcd * 8 + (local & 7);                // local 0..63
    bn = local >> 3;
  }

  __shared__ __align__(16) u16 AL[2][ASLOT];   // 2 x BMx64 bf16
  __shared__ __align__(16) u16 BL[3][6144];    // 3 x 96x64 bf16 = 36 KB

  const int tid = threadIdx.x;
  const int wave = tid >> 6, lane = tid & 63;
  const int lr = lane & 15, lq = lane >> 4;
  const int wm = (wave & 1) * (BM / 2);  // wave row origin
  const int wn = (wave >> 1) * 48;       // wave col origin in 96

  // staging: piece = 32 rows x 64 cols (4KB) = 256 lanes x 16B, linear LDS dest;
  // SOURCE col-chunk carries the inverse of the 3-bit read swizzle:
  // LDS slot (row, chunk) holds logical chunk ^ (row&7).
  const int prow = tid >> 3;                               // 0..31
  const int pcc  = (tid & 7) ^ (prow & 7);                 // 3-bit pre-swizzle
  const u16* Ag = A + (size_t)(bm * BM + prow) * lda + pcc * 8;
  const u16* Bg = Bt + (size_t)(bn * 96 + prow) * ldb + pcc * 8;

  auto stA = [&](int slot, int p, int k) {
    async16(&AL[slot][0] + p * 2048 + tid * 8, Ag + (size_t)(p * 32) * lda + k);
  };
  auto stB = [&](int slot, int p, int k) {
    async16(&BL[slot][0] + p * 2048 + tid * 8, Bg + (size_t)(p * 32) * ldb + k);
  };

  // fragment LDS offsets (u16 units): byte ^= (row&7)<<4, row&7 = bits[9:7] of L
  int aOff[2][MI], bOff[2][3];
#pragma unroll
  for (int kk = 0; kk < 2; ++kk) {
#pragma unroll
    for (int mi = 0; mi < MI; ++mi) {
      int L = (wm + mi * 16 + lr) * 128 + kk * 64 + lq * 16;   // bytes
      L ^= ((L >> 7) & 7) << 4;
      aOff[kk][mi] = L >> 1;
    }
#pragma unroll
    for (int nj = 0; nj < 3; ++nj) {
      int L = (wn + nj * 16 + lr) * 128 + kk * 64 + lq * 16;
      L ^= ((L >> 7) & 7) << 4;
      bOff[kk][nj] = L >> 1;
    }
  }

  f32x4 acc[MI][3];
#pragma unroll
  for (int mi = 0; mi < MI; ++mi)
#pragma unroll
    for (int nj = 0; nj < 3; ++nj) acc[mi][nj] = (f32x4){0.f, 0.f, 0.f, 0.f};

  // prologue: A(0)->slot0 (PA), B(0)->slot0 (3), B(1)->slot1 (3)
#pragma unroll
  for (int p = 0; p < PA; ++p) stA(0, p, 0);
  stB(0, 0, 0); stB(0, 1, 0); stB(0, 2, 0);
  stB(1, 0, 64); stB(1, 1, 64); stB(1, 2, 64);
  asm volatile("s_waitcnt vmcnt(3)" ::: "memory");   // drain A0,B0 (own)
  __builtin_amdgcn_s_barrier();                      // rendezvous: tile0 in LDS
  __builtin_amdgcn_sched_barrier(0);

  int bsR = 0, bsW = 2;
  for (int t = 0; t < NT; ++t) {
    const u16* Ab = &AL[t & 1][0];
    const u16* Bb = &BL[bsR][0];
    const int wAs = (t + 1) & 1;
    const int kA = ((t + 1 < NT) ? t + 1 : NT - 1) * 64;   // tail: re-stage dead slot
    const int kB = ((t + 2 < NT) ? t + 2 : NT - 1) * 64;

    // ---- whole K-tile straight-line (R22, passed): compiler emits counted
    // lgkmcnt interleaving; no intra-tile barriers (slot-disjoint). ----
    bf16x8 a0[MI], b0[3], a1[MI], b1[3];
#pragma unroll
    for (int nj = 0; nj < 3; ++nj) b0[nj] = *(const bf16x8*)(Bb + bOff[0][nj]);
#pragma unroll
    for (int mi = 0; mi < MI; ++mi) a0[mi] = *(const bf16x8*)(Ab + aOff[0][mi]);
#pragma unroll
    for (int p = 0; p < PA; ++p) stA(wAs, p, kA);
    __builtin_amdgcn_s_setprio(1);
#pragma unroll
    for (int mi = 0; mi < MI; ++mi)
#pragma unroll
      for (int nj = 0; nj < 3; ++nj)
        acc[mi][nj] = __builtin_amdgcn_mfma_f32_16x16x32_bf16(a0[mi], b0[nj], acc[mi][nj], 0, 0, 0);
    __builtin_amdgcn_s_setprio(0);
#pragma unroll
    for (int nj = 0; nj < 3; ++nj) b1[nj] = *(const bf16x8*)(Bb + bOff[1][nj]);
#pragma unroll
    for (int mi = 0; mi < MI; ++mi) a1[mi] = *(const bf16x8*)(Ab + aOff[1][mi]);
    stB(bsW, 0, kB); stB(bsW, 1, kB); stB(bsW, 2, kB);
    __builtin_amdgcn_s_setprio(1);
#pragma unroll
    for (int mi = 0; mi < MI; ++mi)
#pragma unroll
      for (int nj = 0; nj < 3; ++nj)
        acc[mi][nj] = __builtin_amdgcn_mfma_f32_16x16x32_bf16(a1[mi], b1[nj], acc[mi][nj], 0, 0, 0);
    __builtin_amdgcn_s_setprio(0);
    // this wave's DS reads must COMPLETE before rendezvous (rule #18 pin),
    // then drain own loads to 3 (B(t+2) in flight) and rendezvous.
    asm volatile("s_waitcnt lgkmcnt(0)" ::: "memory");
    __builtin_amdgcn_sched_barrier(0);
    asm volatile("s_waitcnt vmcnt(3)" ::: "memory");
    __builtin_amdgcn_s_barrier();
    __builtin_amdgcn_sched_barrier(0);

    bsR = (bsR + 1 == 3) ? 0 : bsR + 1;
    bsW = (bsW + 1 == 3) ? 0 : bsW + 1;
  }

  // ---------------- epilogue ----------------
  // C/D layout: col = lane&15, row = (lane>>4)*4 + reg  [verified m89/m91]
  const int r0 = bm * BM + wm + lq * 4;
  const int c0 = bn * 96 + wn + lr;
  float bv[3];
#pragma unroll
  for (int nj = 0; nj < 3; ++nj) bv[nj] = bias[c0 + nj * 16];
#pragma unroll
  for (int mi = 0; mi < MI; ++mi) {
#pragma unroll
    for (int r = 0; r < 4; ++r) {
      const size_t rowoff = (size_t)(r0 + mi * 16 + r) * N;
#pragma unroll
      for (int nj = 0; nj < 3; ++nj) {
        float v = acc[mi][nj][r] + bv[nj];
        if (EPI == 0) {
          // tanh-form GELU: x*(1 - 1/(1+exp(2*(0.79788456x + 0.035677408x^3))))
          float inner = v * fmaf(v * v, 0.0356774081f, 0.7978845608f);
          float e = __builtin_amdgcn_exp2f(2.8853900818f * inner);
          float r1 = __builtin_amdgcn_rcpf(1.0f + e);
          v = v - v * r1;             // e=inf -> r1=0 -> v; e=0 -> r1=1 -> 0
          Out[rowoff + c0 + nj * 16] = f2bf(v);
        } else {
          OutF[rowoff + c0 + nj * 16] = v;   // f32 direct, unique owner
        }
      }
    }
  }
}

extern "C" void kernel_launch(void* const* d_in, const int* in_sizes, int n_in,
                              void* d_out, int out_size, void* d_ws, size_t ws_size,
                              hipStream_t stream) {
  const float* x   = (const float*)d_in[0];
  const float* g1a = (const float*)d_in[1];
  const float* g1b = (const float*)d_in[2];
  const float* g1c = (const float*)d_in[3];
  const float* g1d = (const float*)d_in[4];
  const float* b1  = (const float*)d_in[5];
  const float* g2a = (const float*)d_in[6];
  const float* g2b = (const float*)d_in[7];
  const float* g2c = (const float*)d_in[8];
  const float* g2d = (const float*)d_in[9];
  const float* b2  = (const float*)d_in[10];
  float* out = (float*)d_out;

  char* ws = (char*)d_ws;
  u16* xb   = (u16*)(ws + 0);          // 4096x768 bf16   = 6291456 B
  u16* W1t  = (u16*)(ws + 6291456);    // 3072x768 bf16   = 4718592 B
  u16* W2t  = (u16*)(ws + 11010048);   // 768x3072 bf16   = 4718592 B
  u16* h    = (u16*)(ws + 15728640);   // 4096x3072 bf16  = 25165824 B
  // TT scratch (region beyond h; Part no longer exists)
  float* B12_1 = (float*)(ws + 40894464);            // 9216 f32
  float* B12_2 = (float*)(ws + 40894464 + 36864);    // 9216 f32
  float* C1    = (float*)(ws + 40894464 + 73728);    // 147456 f32
  float* C2    = (float*)(ws + 40894464 + 663552);   // 147456 f32

  // x->bf16 (blocks 0..3071) + TT pre-pass (blocks 3072..4295)
  prep<<<4296, 256, 0, stream>>>((const float4*)x, (ushort4*)xb,
                                 g1a, g1b, g1c, g1d, g2a, g2b, g2c, g2d,
                                 B12_1, B12_2, C1, C2);

  // merged expand: layer1 (blocks 0..287) + layer2 (blocks 288..575)
  tt_expand2<<<576, 256, 0, stream>>>(B12_1, C1, W1t, B12_2, C2, W2t);

  // GEMM1: h = gelu(x @ W1 + b1)  (4096x3072, K=768); 1024 blocks of 128x96
  gemm_bt<0, 1, 12, 128><<<1024, 256, 0, stream>>>(xb, W1t, b1, h, nullptr, 3072, 768, 768);
  // GEMM2: out = h @ W2 + b2  (4096x768, K=3072 un-split); 512 blocks of 64x96
  // = 2 blocks/CU; unique output ownership -> direct f32 stores, no Part/reduce.
  gemm_bt<2, 3, 48, 64><<<512, 256, 0, stream>>>(h, W2t, b2, nullptr, out, 768, 3072, 3072);
}

// Round 11
// 155.864 us; speedup vs baseline: 1.0454x; 1.0454x over previous
//
#include <hip/hip_runtime.h>
#include <cstdint>
#include <cstddef>

typedef unsigned short u16;
typedef __attribute__((ext_vector_type(8))) __bf16 bf16x8;
typedef __attribute__((ext_vector_type(4))) float f32x4;

__device__ __forceinline__ u16 f2bf(float f) {
  unsigned u = __float_as_uint(f);
  u += 0x7FFFu + ((u >> 16) & 1u);   // round-to-nearest-even
  return (u16)(u >> 16);
}

__device__ __forceinline__ float bf2f(u16 h) {
  return __uint_as_float(((unsigned)h) << 16);
}

__device__ __forceinline__ void async16(u16* lds, const u16* g) {
  __builtin_amdgcn_global_load_lds(
      (const __attribute__((address_space(1))) unsigned int*)g,
      (__attribute__((address_space(3))) unsigned int*)lds, 16, 0, 0);
}

// ---------------- prep: x->bf16 (blocks 0..3071) + TT pre-pass (blocks 3072..4295) ----
__global__ __launch_bounds__(256)
void prep(const float4* __restrict__ x4, ushort4* __restrict__ xb4,
          const float* __restrict__ gA1, const float* __restrict__ gB1,
          const float* __restrict__ gC1, const float* __restrict__ gD1,
          const float* __restrict__ gA2, const float* __restrict__ gB2,
          const float* __restrict__ gC2, const float* __restrict__ gD2,
          float* __restrict__ B12_1, float* __restrict__ B12_2,
          float* __restrict__ C1, float* __restrict__ C2) {
  const int b = blockIdx.x;
  const int tid = threadIdx.x;
  if (b < 3072) {
    int i = b * 256 + tid;
    float4 v = x4[i];
    ushort4 o;
    o.x = f2bf(v.x); o.y = f2bf(v.y); o.z = f2bf(v.z); o.w = f2bf(v.w);
    xb4[i] = o;
    return;
  }
  int idx = (b - 3072) * 256 + tid;
  if (idx < 9216) {
    int e = idx;
    int r2 = e % 24; int t = e / 24;
    int fo12 = t % 24, fi12 = t / 24;
    int i2 = fi12 % 4, i1 = fi12 / 4;
    int o2 = fo12 % 6, o1 = fo12 / 6;
    float s = 0.f;
#pragma unroll
    for (int r1 = 0; r1 < 12; ++r1)
      s += gA1[(i1 * 4 + o1) * 12 + r1] * gB1[((r1 * 4 + i2) * 6 + o2) * 24 + r2];
    B12_1[e] = s;
  } else if (idx < 18432) {
    int e = idx - 9216;
    int r2 = e % 24; int t = e / 24;
    int fo12 = t % 16, fi12 = t / 16;
    int i2 = fi12 % 6, i1 = fi12 / 6;
    int o2 = fo12 % 4, o1 = fo12 / 4;
    float s = 0.f;
#pragma unroll
    for (int r1 = 0; r1 < 12; ++r1)
      s += gA2[(i1 * 4 + o1) * 12 + r1] * gB2[((r1 * 6 + i2) * 4 + o2) * 24 + r2];
    B12_2[e] = s;
  } else if (idx < 165888) {
    int e = idx - 18432;
    int fi34 = e % 48; int t = e / 48;
    int fo34 = t % 128;
    int i3 = fi34 / 8, i4 = fi34 % 8;
    int o3 = fo34 / 16, o4 = fo34 % 16;
    int r2 = t / 128;
    float s = 0.f;
#pragma unroll
    for (int r3 = 0; r3 < 12; ++r3)
      s += gC1[((r2 * 6 + i3) * 8 + o3) * 12 + r3] * gD1[(r3 * 8 + i4) * 16 + o4];
    C1[e] = s;
  } else {
    int e = idx - 165888;
    int fi34 = e % 128; int t = e / 128;
    int fo34 = t % 48;
    int i3 = fi34 / 16, i4 = fi34 % 16;
    int o3 = fo34 / 8, o4 = fo34 % 8;
    int r2 = t / 48;
    float s = 0.f;
#pragma unroll
    for (int r3 = 0; r3 < 12; ++r3)
      s += gC2[((r2 * 8 + i3) * 6 + o3) * 12 + r3] * gD2[(r3 * 16 + i4) * 8 + o4];
    C2[e] = s;
  }
}

// ---------------- TT expand (device body): Wt[out][in] = sum_r2 B12*C34t ----------------
template <int FI12, int I34, int O12, int O34, int OG>
__device__ __forceinline__
void tt_expand_body(const float* __restrict__ B12, const float* __restrict__ C34t,
                    u16* __restrict__ Wt, int bx, int by, int tid, float* sB) {
  constexpr int R2 = 24;
  constexpr int Kin = FI12 * I34;
  constexpr int IC = Kin / 8;
  constexpr int I34C = I34 / 8;
  for (int e = tid; e < FI12 * OG * R2; e += 256) {
    int r2 = e % R2; int t = e / R2;
    int f = t % OG; int fi12 = t / OG;
    sB[(fi12 * OG + f) * 25 + r2] = B12[(fi12 * O12 + by * OG + f) * R2 + r2];
  }
  __syncthreads();
  const int t = bx * 256 + tid;
  const int fo34 = t / IC;
  const int ic = t % IC;
  const int fi12 = ic / I34C;
  const int fi34 = (ic % I34C) * 8;

  float acc[OG][8];
#pragma unroll
  for (int f = 0; f < OG; ++f)
#pragma unroll
    for (int k = 0; k < 8; ++k) acc[f][k] = 0.f;

  for (int r2 = 0; r2 < R2; ++r2) {
    const float4* cp = (const float4*)(C34t + ((size_t)(r2 * O34 + fo34) * I34 + fi34));
    float4 c0 = cp[0], c1 = cp[1];
    float c[8] = {c0.x, c0.y, c0.z, c0.w, c1.x, c1.y, c1.z, c1.w};
#pragma unroll
    for (int f = 0; f < OG; ++f) {
      float bb = sB[(fi12 * OG + f) * 25 + r2];
#pragma unroll
      for (int k = 0; k < 8; ++k) acc[f][k] += bb * c[k];
    }
  }
#pragma unroll
  for (int f = 0; f < OG; ++f) {
    int out = (by * OG + f) * O34 + fo34;
    u16 v[8];
#pragma unroll
    for (int k = 0; k < 8; ++k) v[k] = f2bf(acc[f][k]);
    *(uint4*)(Wt + (size_t)out * Kin + fi12 * I34 + fi34) = *(const uint4*)v;
  }
}

// Merged: blocks 0..287 -> layer1 (48x6); blocks 288..575 -> layer2 (72x4)
__global__ __launch_bounds__(256)
void tt_expand2(const float* __restrict__ B12_1, const float* __restrict__ C1, u16* __restrict__ W1t,
                const float* __restrict__ B12_2, const float* __restrict__ C2, u16* __restrict__ W2t) {
  __shared__ float sB[24 * 4 * 25];
  const int b = blockIdx.x;
  const int tid = threadIdx.x;
  if (b < 288) {
    tt_expand_body<16, 48, 24, 128, 4>(B12_1, C1, W1t, b % 48, b / 48, tid, sB);
  } else {
    int bb = b - 288;
    tt_expand_body<24, 128, 16, 48, 4>(B12_2, C2, W2t, bb % 72, bb / 72, tid, sB);
  }
}

// out = bias2 + sum of nz bf16 partials; 8 elems/thread, 16B partial loads
__global__ void reduceN8(const uint4* __restrict__ P, const float* __restrict__ bias,
                         float4* __restrict__ out4, int n8, int zstride8, int nz) {
  int i = blockIdx.x * 256 + threadIdx.x;
  if (i >= n8) return;
  int b0 = (i % 96) * 8;
  float a[8];
#pragma unroll
  for (int k = 0; k < 8; ++k) a[k] = bias[b0 + k];
  for (int s = 0; s < nz; ++s) {
    uint4 u = P[i + s * zstride8];
    const u16* up = (const u16*)&u;
#pragma unroll
    for (int k = 0; k < 8; ++k) a[k] += bf2f(up[k]);
  }
  out4[i * 2]     = (float4){a[0], a[1], a[2], a[3]};
  out4[i * 2 + 1] = (float4){a[4], a[5], a[6], a[7]};
}

// ---- bf16 MFMA GEMM: FINAL (best-measured, R4 = 157.86us) ----
// Session ledger: six structurally distinct schedules (2ph/3blk R1, 8ph/1blk
// R16, deep-2ph/2blk R17, 3-bit swizzle R18, 1-barrier straight-line R22,
// narrow-M direct R23) all execute at ~537 TF — time tracks FLOPs with a
// constant coefficient, insensitive to barrier count, LDS bank conflicts
// (R0 counter: ~9%/CU), staging depth, tile aspect, and K-split. Consolidation
// attempts: R19 atomics (-13us, cross-XCD serialization), R20 no-split
// (1 blk/CU TLP loss), R23 narrow-M (traffic ratio) — bf16 partials + reduce
// is the measured optimum for the GEMM2 chain. This file locks the best-
// measured configuration: tile 128x96, 4 waves (2Mx2N, 64x48/wave), BK=64,
// 2 phases/K-tile, A 2-deep + B 3-deep = 68KB -> 2 blocks/CU, counted
// vmcnt(3) ledger (wait-BEFORE-barrier; vmcnt is per-wave), setprio around
// MFMA clusters, both-sides LDS swizzle, XCD L2-rects, tanh-GELU epilogue,
// gemm2 K-split-2 + reduceN8 (nz=2).
template <bool GELU, int MAP, int NT>
__global__ __launch_bounds__(256, 2)
void gemm_bt(const u16* __restrict__ A, const u16* __restrict__ Bt,
             const float* __restrict__ bias, u16* __restrict__ Out,
             int N, int lda, int ldb, size_t zstride) {
  const int flat = blockIdx.x;
  const int xcd = flat & 7;            // HW round-robins blockIdx over 8 XCDs
  const int local = flat >> 3;
  int bm, bn, bz;
  if (MAP == 1) {                      // GEMM1: 32bm x 32bn; XCD rect 8bm x 16bn
    bm = (xcd >> 1) * 8 + (local & 7);         // local 0..127
    bn = (xcd & 1) * 16 + (local >> 3);
    bz = 0;
  } else {                             // GEMM2: 32bm x 8bn x 2bz; XCD: 8bm x 8bn x 1bz
    bz = xcd & 1;
    bm = (xcd >> 1) * 8 + (local & 7);         // local 0..63
    bn = local >> 3;
  }
  const int kbeg = (MAP == 2) ? bz * 1536 : 0;

  __shared__ __align__(16) u16 AL[2][8192];    // 2 x 128x64 bf16 = 32 KB
  __shared__ __align__(16) u16 BL[3][6144];    // 3 x  96x64 bf16 = 36 KB

  const int tid = threadIdx.x;
  const int wave = tid >> 6, lane = tid & 63;
  const int lr = lane & 15, lq = lane >> 4;
  const int wm = (wave & 1) * 64;      // wave row origin in 128
  const int wn = (wave >> 1) * 48;     // wave col origin in 96

  // staging: piece = 32 rows x 64 cols (4KB) = 256 lanes x 16B, linear LDS dest;
  // SOURCE col-chunk pre-swizzled so swizzled reads see logical data.
  const int prow = tid >> 3;                               // 0..31
  const int pcc  = (tid & 7) ^ (((tid >> 5) & 1) << 1);    // bit5(tid)=bit2(row)
  const u16* Ag = A + (size_t)(bm * 128 + prow) * lda + kbeg + pcc * 8;
  const u16* Bg = Bt + (size_t)(bn * 96 + prow) * ldb + kbeg + pcc * 8;

  auto stA = [&](int slot, int p, int k) {
    async16(&AL[slot][0] + p * 2048 + tid * 8, Ag + (size_t)(p * 32) * lda + k);
  };
  auto stB = [&](int slot, int p, int k) {
    async16(&BL[slot][0] + p * 2048 + tid * 8, Bg + (size_t)(p * 32) * ldb + k);
  };

  // fragment LDS offsets (u16 units), same XOR as the staged source permutation
  int aOff[2][4], bOff[2][3];
#pragma unroll
  for (int kk = 0; kk < 2; ++kk) {
#pragma unroll
    for (int mi = 0; mi < 4; ++mi) {
      int L = (wm + mi * 16 + lr) * 128 + kk * 64 + lq * 16;   // bytes
      L ^= ((L >> 9) & 1) << 5;
      aOff[kk][mi] = L >> 1;
    }
#pragma unroll
    for (int nj = 0; nj < 3; ++nj) {
      int L = (wn + nj * 16 + lr) * 128 + kk * 64 + lq * 16;
      L ^= ((L >> 9) & 1) << 5;
      bOff[kk][nj] = L >> 1;
    }
  }

  f32x4 acc[4][3];
#pragma unroll
  for (int mi = 0; mi < 4; ++mi)
#pragma unroll
    for (int nj = 0; nj < 3; ++nj) acc[mi][nj] = (f32x4){0.f, 0.f, 0.f, 0.f};

  // prologue: A(0)->slot0 (4), B(0)->slot0 (3), B(1)->slot1 (3) = 10 in flight
  stA(0, 0, 0); stA(0, 1, 0); stA(0, 2, 0); stA(0, 3, 0);
  stB(0, 0, 0); stB(0, 1, 0); stB(0, 2, 0);
  stB(1, 0, 64); stB(1, 1, 64); stB(1, 2, 64);
  asm volatile("s_waitcnt vmcnt(3)" ::: "memory");   // drain A0,B0 (own)
  __builtin_amdgcn_s_barrier();                      // rendezvous: tile0 in LDS
  __builtin_amdgcn_sched_barrier(0);

  int bsR = 0, bsW = 2;
  for (int t = 0; t < NT; ++t) {
    const u16* Ab = &AL[t & 1][0];
    const u16* Bb = &BL[bsR][0];
    const int wAs = (t + 1) & 1;
    const int kA = ((t + 1 < NT) ? t + 1 : NT - 1) * 64;   // tail: re-stage dead slot
    const int kB = ((t + 2 < NT) ? t + 2 : NT - 1) * 64;

    bf16x8 bf[3], af[4];
    // ---- phase 1: kk=0 (12 MFMA); stage A(t+1) 4 pieces ----
#pragma unroll
    for (int nj = 0; nj < 3; ++nj) bf[nj] = *(const bf16x8*)(Bb + bOff[0][nj]);
#pragma unroll
    for (int mi = 0; mi < 4; ++mi) af[mi] = *(const bf16x8*)(Ab + aOff[0][mi]);
    stA(wAs, 0, kA); stA(wAs, 1, kA); stA(wAs, 2, kA); stA(wAs, 3, kA);
    __builtin_amdgcn_s_barrier();
    asm volatile("s_waitcnt lgkmcnt(0)" ::: "memory");
    __builtin_amdgcn_sched_barrier(0);
    __builtin_amdgcn_s_setprio(1);
#pragma unroll
    for (int mi = 0; mi < 4; ++mi)
#pragma unroll
      for (int nj = 0; nj < 3; ++nj)
        acc[mi][nj] = __builtin_amdgcn_mfma_f32_16x16x32_bf16(af[mi], bf[nj], acc[mi][nj], 0, 0, 0);
    __builtin_amdgcn_s_setprio(0);
    __builtin_amdgcn_s_barrier();
    __builtin_amdgcn_sched_barrier(0);
    // ---- phase 2: kk=1 (12 MFMA); stage B(t+2) 3 pieces; end-of-tile wait ----
#pragma unroll
    for (int nj = 0; nj < 3; ++nj) bf[nj] = *(const bf16x8*)(Bb + bOff[1][nj]);
#pragma unroll
    for (int mi = 0; mi < 4; ++mi) af[mi] = *(const bf16x8*)(Ab + aOff[1][mi]);
    stB(bsW, 0, kB); stB(bsW, 1, kB); stB(bsW, 2, kB);
    __builtin_amdgcn_s_barrier();
    asm volatile("s_waitcnt lgkmcnt(0)" ::: "memory");
    __builtin_amdgcn_sched_barrier(0);
    __builtin_amdgcn_s_setprio(1);
#pragma unroll
    for (int mi = 0; mi < 4; ++mi)
#pragma unroll
      for (int nj = 0; nj < 3; ++nj)
        acc[mi][nj] = __builtin_amdgcn_mfma_f32_16x16x32_bf16(af[mi], bf[nj], acc[mi][nj], 0, 0, 0);
    __builtin_amdgcn_s_setprio(0);
    // drain own loads to 3 (B(t+2)); THEN rendezvous (vmcnt is per-wave):
    // after this barrier tile t+1's A and B are in LDS for every wave.
    asm volatile("s_waitcnt vmcnt(3)" ::: "memory");
    __builtin_amdgcn_s_barrier();
    __builtin_amdgcn_sched_barrier(0);

    bsR = (bsR + 1 == 3) ? 0 : bsR + 1;
    bsW = (bsW + 1 == 3) ? 0 : bsW + 1;
  }

  // ---------------- epilogue ----------------
  u16* Op = Out + (size_t)bz * zstride;
  // C/D layout: col = lane&15, row = (lane>>4)*4 + reg  [verified m89/m91]
  const int r0 = bm * 128 + wm + lq * 4;
  const int c0 = bn * 96 + wn + lr;
  float bv[3];
  if (GELU) {
#pragma unroll
    for (int nj = 0; nj < 3; ++nj) bv[nj] = bias[c0 + nj * 16];
  }
#pragma unroll
  for (int mi = 0; mi < 4; ++mi) {
#pragma unroll
    for (int r = 0; r < 4; ++r) {
      const size_t rowoff = (size_t)(r0 + mi * 16 + r) * N;
#pragma unroll
      for (int nj = 0; nj < 3; ++nj) {
        float v = acc[mi][nj][r];
        if (GELU) {
          v += bv[nj];
          // tanh-form GELU: x*(1 - 1/(1+exp(2*(0.79788456x + 0.035677408x^3))))
          float inner = v * fmaf(v * v, 0.0356774081f, 0.7978845608f);
          float e = __builtin_amdgcn_exp2f(2.8853900818f * inner);
          float r1 = __builtin_amdgcn_rcpf(1.0f + e);
          v = v - v * r1;             // e=inf -> r1=0 -> v; e=0 -> r1=1 -> 0
        }
        Op[rowoff + c0 + nj * 16] = f2bf(v);
      }
    }
  }
}

extern "C" void kernel_launch(void* const* d_in, const int* in_sizes, int n_in,
                              void* d_out, int out_size, void* d_ws, size_t ws_size,
                              hipStream_t stream) {
  const float* x   = (const float*)d_in[0];
  const float* g1a = (const float*)d_in[1];
  const float* g1b = (const float*)d_in[2];
  const float* g1c = (const float*)d_in[3];
  const float* g1d = (const float*)d_in[4];
  const float* b1  = (const float*)d_in[5];
  const float* g2a = (const float*)d_in[6];
  const float* g2b = (const float*)d_in[7];
  const float* g2c = (const float*)d_in[8];
  const float* g2d = (const float*)d_in[9];
  const float* b2  = (const float*)d_in[10];
  float* out = (float*)d_out;

  char* ws = (char*)d_ws;
  u16* xb   = (u16*)(ws + 0);          // 4096x768 bf16   = 6291456 B
  u16* W1t  = (u16*)(ws + 6291456);    // 3072x768 bf16   = 4718592 B
  u16* W2t  = (u16*)(ws + 11010048);   // 768x3072 bf16   = 4718592 B
  u16* h    = (u16*)(ws + 15728640);   // 4096x3072 bf16  = 25165824 B
  u16* Part = (u16*)(ws + 40894464);   // 2 x 4096x768 bf16 = 12582912 B
  // TT scratch ALIASES Part (dead before gemm2 writes Part; stream-ordered)
  float* B12_1 = (float*)(ws + 40894464);            // 9216 f32
  float* B12_2 = (float*)(ws + 40894464 + 36864);    // 9216 f32
  float* C1    = (float*)(ws + 40894464 + 73728);    // 147456 f32
  float* C2    = (float*)(ws + 40894464 + 663552);   // 147456 f32

  // x->bf16 (blocks 0..3071) + TT pre-pass (blocks 3072..4295)
  prep<<<4296, 256, 0, stream>>>((const float4*)x, (ushort4*)xb,
                                 g1a, g1b, g1c, g1d, g2a, g2b, g2c, g2d,
                                 B12_1, B12_2, C1, C2);

  // merged expand: layer1 (blocks 0..287) + layer2 (blocks 288..575)
  tt_expand2<<<576, 256, 0, stream>>>(B12_1, C1, W1t, B12_2, C2, W2t);

  // GEMM1: h = gelu(x @ W1 + b1)  (4096x3072, K=768); 1024 blocks of 128x96
  gemm_bt<true, 1, 12><<<1024, 256, 0, stream>>>(xb, W1t, b1, h, 3072, 768, 768, 0);
  // GEMM2: bf16 partials, K=3072 split 2 ways; 512 blocks of 128x96
  gemm_bt<false, 2, 24><<<512, 256, 0, stream>>>(h, W2t, nullptr, Part, 768, 3072, 3072, 3145728);
  // out = b2 + sum(2 partials)
  reduceN8<<<1536, 256, 0, stream>>>((const uint4*)Part, b2,
                                     (float4*)out, 393216, 393216, 2);
}